// Round 10
// baseline (32.170 us; speedup 1.0000x reference)
//
#include <hip/hip_runtime.h>

// Problem constants
#define NSTEPS 255
#define NTRAJ  16384
#define NBLK   256          // integration blocks; 64 trajectories each
#define ROWB   2040         // bytes per wvec row = 255 steps * 8 B (8-mod-16!)

#define GAMMA_F 0.36f
#define OMEGA_F 5.0265f
#define DT_F    0.00390625f          // 2^-8
#define CW      0.0375f              // sqrt(GAMMA)*sqrt(DT) = 0.6/16 (exact)
#define GD      (GAMMA_F * DT_F)
#define OD      (OMEGA_F * DT_F)

// LDS state history (R7/R9-validated): [slot][lane] fp16x4, pitch 520 B.
#define PITCH  520
#define STATEB 132608        // 255*520 = 132600, padded

// w-tiles: 16 steps x 64 rows, 128 B/row, col-swizzled (c' = (c+r)&15) so
// both producer b64 writes and consumer b64 reads are <=4-way (free-ish).
// 3 tiles (triple buffer). Total smem = 132608 + 3*8192 = 157184 <= 160 KiB.
#define TILEB  8192

typedef __fp16 half2v __attribute__((ext_vector_type(2)));
typedef float  f32x2  __attribute__((ext_vector_type(2)));

__device__ __forceinline__ unsigned pk2(float a, float b) {
  half2v h = __builtin_amdgcn_cvt_pkrtz(a, b);
  return __builtin_bit_cast(unsigned, h);
}

// One Euler-Maruyama step (bit-identical to R4/R7/R9 validated math).
#define STEP2(wx_, wy_, ii_) {                                                  \
  const float w0  = (wx_) * CW;                                                 \
  const float cy  = (wy_) * CW;                                                 \
  const f32x2 sw  = __builtin_shufflevector(v, v, 1, 0);   /* (y,x) */          \
  f32x2 t = __builtin_elementwise_fma(epack, sw, v);                            \
  t = __builtin_elementwise_fma(mGD2, v, t);                                    \
  const f32x2 w0s = {w0, w0};                                                   \
  t = __builtin_elementwise_fma(-(v * z), w0s, t);                              \
  const f32x2 cys = {-cy, cy};                                                  \
  t = __builtin_elementwise_fma(sw, cys, t);                                    \
  t[1] = __builtin_fmaf(-OD, z, t[1]);                                          \
  const float a_ = __builtin_fmaf(OD, v[1], z);                                 \
  const float r_ = __builtin_fmaf(-(z * z), w0, w0);                            \
  v = t; z = a_ + r_;                                                           \
  *(uint2*)(sb + (ii_) * PITCH) = make_uint2(pk2(v[0], v[1]), pk2(z, 0.0f));    \
}

// Producer: load chunk c (64 rows x 16 float2) cooperatively, 192 threads.
// Element e -> row r=e>>4, col c0=e&15; addr always 8-aligned. Chunk 15 is
// short (15 cols): guard skips c0==15 (avoids reading 8 B past wvec's end,
// which is exactly a page boundary).
#define PLOAD(R, c) {                                                           \
  _Pragma("unroll")                                                             \
  for (int i_ = 0; i_ < 6; ++i_) {                                              \
    const int e_ = p + 192 * i_;                                                \
    if (e_ < 1024 && ((c) < 15 || (e_ & 15) < 15))                              \
      R[i_] = *(const float2*)(wbase + (size_t)(e_ >> 4) * ROWB                 \
                               + (size_t)(c) * 128 + (e_ & 15) * 8);            \
  }                                                                             \
}

// Producer: write held regs to tile (c%3) with col swizzle c' = (c0+r)&15.
#define PWRITE(R, c) {                                                          \
  char* const tb_ = tiles + ((c) % 3) * TILEB;                                  \
  _Pragma("unroll")                                                             \
  for (int i_ = 0; i_ < 6; ++i_) {                                              \
    const int e_ = p + 192 * i_;                                                \
    if (e_ < 1024 && ((c) < 15 || (e_ & 15) < 15)) {                            \
      const int r_ = e_ >> 4, c0_ = e_ & 15;                                    \
      *(float2*)(tb_ + r_ * 128 + (((c0_ + r_) & 15) * 8)) = R[i_];             \
    }                                                                           \
  }                                                                             \
}

// Consumer: run NK steps of chunk k from tile (k%3); lane l reads its row l
// with the matching swizzle. Advances sb.
#define CCHUNK(k_, NK) {                                                        \
  const char* tb_ = tiles + ((k_) % 3) * TILEB + l * 128;                       \
  _Pragma("unroll")                                                             \
  for (int p_ = 0; p_ < (NK); ++p_) {                                           \
    const float2 w2 = *(const float2*)(tb_ + (((p_ + l) & 15) * 8));            \
    STEP2(w2.x, w2.y, p_);                                                      \
  }                                                                             \
  sb += (NK) * PITCH;                                                           \
}

// grid = 256 blocks x 256 threads (4 waves). Wave 0: integrate 64 trajectories
// (math/state path bit-identical to R9). Waves 1-3: coalesced w-load engine
// into triple-buffered LDS tiles. One __syncthreads per chunk.
// Chunks: 0..14 = 16 steps, 15 = 15 steps (total 255).
__global__ __launch_bounds__(256) void sde_integrate(const float* __restrict__ inp,
                                                     const float* __restrict__ wvec,
                                                     float* __restrict__ partial) {
  __shared__ alignas(16) char smem[STATEB + 3 * TILEB];
  char* const tiles = smem + STATEB;
  const int g   = blockIdx.x;
  const int tid = threadIdx.x;
  const int wid = tid >> 6;
  const int l   = tid & 63;
  const int p   = tid - 64;            // producer linear id 0..191 (waves 1-3)

  // consumer setup (harmless for producers)
  const float eps = inp[l & 31];       // trajectory n = g*64+l; eps = inp[n%32]
  const f32x2 epack = {-eps * DT_F, eps * DT_F};
  const f32x2 mGD2  = {-GD, -GD};
  char* sb = smem + l * 8;
  f32x2 v = {0.0f, 0.0f};
  float z = 1.0f;

  const char* wbase = (const char*)wvec + (size_t)g * 64 * ROWB;
  float2 rA[6] = {}, rB[6] = {};

  if (wid > 0) {                       // producer prologue: tiles 0,1 ready,
    PLOAD(rA, 0);                      // chunk 2 in flight in rA
    PLOAD(rB, 1);
    PWRITE(rA, 0);
    PLOAD(rA, 2);
    PWRITE(rB, 1);
  }
  __syncthreads();

  #pragma unroll 1
  for (int k = 0; k < 16; ++k) {
    if (wid > 0) {
      if (k + 2 < 16) {
        if (k & 1) { PWRITE(rB, k + 2); if (k + 3 < 16) PLOAD(rA, k + 3); }
        else       { PWRITE(rA, k + 2); if (k + 3 < 16) PLOAD(rB, k + 3); }
      }
    } else {
      if (k < 15) { CCHUNK(k, 16); }
      else        { CCHUNK(k, 15); }
    }
    __syncthreads();
  }

  // Tail: 1 slot per thread (255 active), same per-slot order as R9
  // (j ascending, f32x2 xy accumulate) -> bit-identical partials.
  const int s = tid;
  if (s < NSTEPS) {
    const char* rb = smem + (size_t)s * PITCH;
    f32x2 sxy = {0.0f, 0.0f};
    float fz = 0.0f;
    #pragma unroll
    for (int j = 0; j < 64; ++j) {
      const uint2 u = *(const uint2*)(rb + j * 8);
      const half2v xy = __builtin_bit_cast(half2v, u.x);
      const half2v zp = __builtin_bit_cast(half2v, u.y);
      const f32x2 vxy = {(float)xy[0], (float)xy[1]};
      sxy += vxy;
      fz += (float)zp[0];
    }
    float* pp = partial + ((size_t)g * NSTEPS + s) * 3;
    pp[0] = sxy[0]; pp[1] = sxy[1]; pp[2] = fz;
  }
}

// one thread per (b, t): sum 8 block-partials, emit 6 probabilities.
__global__ __launch_bounds__(64) void sde_finalize(const float* __restrict__ partial,
                                                   float* __restrict__ out) {
  const int idx = blockIdx.x * 64 + threadIdx.x;   // b*256 + t, 8192 total
  const int b = idx >> 8;
  const int t = idx & 255;
  float* o = out + (size_t)idx * 6;

  if (t == 0) {
    o[0] = 0.5f; o[1] = 0.5f; o[2] = 0.5f; o[3] = 0.5f;
    o[4] = 1.0f; o[5] = 0.0f;
    return;
  }

  float sx = 0.0f, sy = 0.0f, sz = 0.0f;
  #pragma unroll
  for (int j = 0; j < 8; ++j) {
    const float* pp = partial + ((size_t)(b * 8 + j) * NSTEPS + (t - 1)) * 3;
    sx += pp[0]; sy += pp[1]; sz += pp[2];
  }
  const float inv = 1.0f / 512.0f;
  const float mx = sx * inv, my = sy * inv, mz = sz * inv;
  o[0] = 0.5f * (1.0f + mx);
  o[1] = 0.5f * (1.0f - mx);
  o[2] = 0.5f * (1.0f + my);
  o[3] = 0.5f * (1.0f - my);
  o[4] = 0.5f * (1.0f + mz);
  o[5] = 0.5f * (1.0f - mz);
}

extern "C" void kernel_launch(void* const* d_in, const int* in_sizes, int n_in,
                              void* d_out, int out_size, void* d_ws, size_t ws_size,
                              hipStream_t stream) {
  (void)in_sizes; (void)n_in; (void)out_size; (void)ws_size;
  const float* inp  = (const float*)d_in[0];   // [32]
  const float* wvec = (const float*)d_in[1];   // [16384][255][2]
  float* out     = (float*)d_out;              // [32][256][6]
  float* partial = (float*)d_ws;               // 256*255*3*4 = 783360 B

  sde_integrate<<<NBLK, 256, 0, stream>>>(inp, wvec, partial);
  sde_finalize<<<128, 64, 0, stream>>>(partial, out);
}